// Round 11
// baseline (279.755 us; speedup 1.0000x reference)
//
#include <hip/hip_runtime.h>
#include <cstdint>
#include <cstddef>

typedef unsigned long long u64;
typedef unsigned int u32;

#define SLICES 2
#define SCAND 192           // per-slice pool capacity
#define CAND 384            // SLICES * SCAND
#define NSLOT 6             // CAND / 64
#define NBINS 4096
#define SEL_THR 1024
#define SEL_TARGET 128
#define POOLCAP 4096
#define MASKW 3200          // 102400 columns max as bits
#define TOP8 8

// IoU exactly as reference _box_iou, all f32 IEEE ops (bit-exact, absmax=0 rounds 1-10).
__device__ __forceinline__ float iou_f32(float4 p, float4 t, float area_t) {
  float area1 = (p.z - p.x) * (p.w - p.y);
  float ltx = fmaxf(p.x, t.x);
  float lty = fmaxf(p.y, t.y);
  float rbx = fminf(p.z, t.z);
  float rby = fminf(p.w, t.w);
  float wx = fmaxf(rbx - ltx, 0.0f);
  float wy = fmaxf(rby - lty, 0.0f);
  float inter = wx * wy;
  return inter / (area1 + area_t - inter);
}

__device__ __forceinline__ u64 map_cost(double cur) {
  u64 b = (u64)__double_as_longlong(cur);
  if (b == 0x8000000000000000ull) b = 0;                 // canonicalize -0 -> +0
  return (b >> 63) ? ~b : (b | 0x8000000000000000ull);   // order-exact total map
}
__device__ __forceinline__ double unmap_cost(u64 m) {
  u64 b = (m >> 63) ? (m ^ 0x8000000000000000ull) : ~m;
  return __longlong_as_double((long long)b);
}

// Key encoding: (io_bits << 32) | (0xFFFFFFFF - col). Raw u64 max = (io desc, col asc).

// Kernel A: unchanged (proven absmax=0 rounds 8-10).
__global__ __launch_bounds__(SEL_THR) void select_kernel(const float4* __restrict__ pbox,
                                                         const float4* __restrict__ tbox,
                                                         u64* __restrict__ ckey,
                                                         int M, int NROWS) {
  __shared__ u32 s_hist[NBINS];
  __shared__ int s_csum[SEL_THR];
  __shared__ u64 s_pool[POOLCAP];
  __shared__ int s_n, s_n2, s_B;
  const int tid = threadIdx.x;
  const int lane = tid & 63;
  const int slice = blockIdx.x, row = blockIdx.y;
  const int sw = (M + SLICES - 1) / SLICES;
  const int base = slice * sw;
  const int send = min(base + sw, M);
  const float4 tb = tbox[row];
  const float area_t = (tb.z - tb.x) * (tb.w - tb.y);
  u64* orow_key = ckey + (size_t)row * CAND + slice * SCAND;

  for (int b = tid; b < NBINS; b += SEL_THR) s_hist[b] = 0;
  if (tid == 0) { s_n = 0; s_n2 = 0; s_B = 0; }
  __syncthreads();

  const u64 lowmask = (1ull << lane) - 1ull;
  const int iters = (sw + SEL_THR - 1) / SEL_THR;
  for (int it = 0; it < iters; ++it) {
    int j = base + it * SEL_THR + tid;
    bool inr = (j < send);
    float io = -1.0f;
    if (inr) io = iou_f32(pbox[j], tb, area_t);
    bool pos = inr && (io > 0.0f);
    u64 pm = __ballot(pos);
    int wn = (int)__popcll(pm);
    if (wn) {
      int wb = 0;
      if (lane == 0) wb = atomicAdd(&s_n, wn);
      wb = __shfl(wb, 0);
      if (pos) {
        int idx = wb + (int)__popcll(pm & lowmask);
        if (idx < POOLCAP) s_pool[idx] = ((u64)__float_as_uint(io) << 32) | (u64)(0xFFFFFFFFu - (u32)j);
        atomicAdd(&s_hist[__float_as_uint(io) >> 18], 1u);
      }
    }
  }
  __syncthreads();
  const int np = s_n;

  {
    int b0 = tid * 4;
    s_csum[tid] = (int)(s_hist[b0] + s_hist[b0 + 1] + s_hist[b0 + 2] + s_hist[b0 + 3]);
  }
  __syncthreads();

  if (tid < 64) {
    if (np >= SEL_TARGET) {
      int R = 0; bool found = false;
      for (int ch = SEL_THR / 64 - 1; ch >= 0 && !found; --ch) {
        int cum = s_csum[ch * 64 + tid];
        for (int off = 1; off < 64; off <<= 1) {
          int o = __shfl_down(cum, off);
          if (tid + off < 64) cum += o;
        }
        int chunksum = __shfl(cum, 0);
        if (R + chunksum >= SEL_TARGET) {
          u64 m = __ballot(R + cum >= SEL_TARGET);
          int l = 63 - __clzll(m);
          int R2 = R + ((l < 63) ? __shfl(cum, l + 1) : 0);
          if (tid == 0) {
            int bb = (ch * 64 + l) * 4;
            int B2 = bb;
            for (int b = bb + 3; b >= bb; --b) {
              R2 += (int)s_hist[b];
              if (R2 >= SEL_TARGET) { B2 = b; break; }
            }
            s_B = B2;
          }
          found = true;
        } else R += chunksum;
      }
    }
  }
  __syncthreads();
  const int B = s_B;

  if (np >= SEL_TARGET) {
    if (np <= POOLCAP) {
      for (int t = tid; t < np; t += SEL_THR) {
        u64 k = s_pool[t];
        if ((u32)(k >> 50) >= (u32)B) {
          int pos = atomicAdd(&s_n2, 1);
          if (pos < SCAND) orow_key[pos] = k;
        }
      }
    } else {
      for (int j = base + tid; j < send; j += SEL_THR) {
        float io = iou_f32(pbox[j], tb, area_t);
        if (io > 0.0f && (int)(__float_as_uint(io) >> 18) >= B) {
          int pos = atomicAdd(&s_n2, 1);
          if (pos < SCAND) orow_key[pos] = ((u64)__float_as_uint(io) << 32) | (u64)(0xFFFFFFFFu - (u32)j);
        }
      }
    }
    __syncthreads();
  } else {
    for (int t = tid; t < np; t += SEL_THR) {
      u64 k = s_pool[t];
      int pos = atomicAdd(&s_n2, 1);
      if (pos < SCAND) orow_key[pos] = k;
    }
    __syncthreads();
    if (tid < 64) {
      int need = SEL_TARGET - np, got = 0;
      int base_n = s_n2;
      for (int b2 = base; b2 < send && got < need; b2 += 64) {
        int j = b2 + tid;
        float io = (j < send) ? iou_f32(pbox[j], tb, area_t) : -1.0f;
        bool z = (j < send) && (io == 0.0f);
        u64 zm = __ballot(z);
        int rank = (int)__popcll(zm & ((1ull << tid) - 1ull));
        if (z && rank < need - got) {
          int pos = base_n + got + rank;
          if (pos < SCAND) orow_key[pos] = (u64)(0xFFFFFFFFu - (u32)j);
        }
        int zn = (int)__popcll(zm); if (zn > need - got) zn = need - got;
        got += zn;
      }
      if (tid == 0) s_n2 = base_n + got;
    }
    __syncthreads();
  }
  int n = min(s_n2, SCAND);
  for (int t2 = n + tid; t2 < SCAND; t2 += SEL_THR) orow_key[t2] = 0ull;
}

// owned-min DPP reduce step (identity: key=~0, col=INT_MAX); result lands lane 63
#define DPP_STEP(CTRL) do { \
  u32 ohi = (u32)__builtin_amdgcn_update_dpp((int)0xFFFFFFFF, (int)khi, (CTRL), 0xF, 0xF, false); \
  u32 olo = (u32)__builtin_amdgcn_update_dpp((int)0xFFFFFFFF, (int)klo, (CTRL), 0xF, 0xF, false); \
  int ocl =      __builtin_amdgcn_update_dpp((int)0x7FFFFFFF, kcol,     (CTRL), 0xF, 0xF, false); \
  bool lt = (ohi < khi) || (ohi == khi && ((olo < klo) || (olo == klo && ocl < kcol))); \
  if (lt) { khi = ohi; klo = olo; kcol = ocl; } \
} while (0)

// max DPP step (identity: 0)
#define DPPMAX(CTRL) do { \
  u32 oh2 = (u32)__builtin_amdgcn_update_dpp(0, (int)mhi, (CTRL), 0xF, 0xF, false); \
  u32 ol2 = (u32)__builtin_amdgcn_update_dpp(0, (int)mlo, (CTRL), 0xF, 0xF, false); \
  bool gt = (oh2 > mhi) || (oh2 == mhi && ol2 > mlo); \
  if (gt) { mhi = oh2; mlo = ol2; } \
} while (0)

// Kernel A2: exact top-8 of each row's pool by u64 key + candidate boxes.
__global__ __launch_bounds__(64) void top8_kernel(const float4* __restrict__ pbox,
                                                  const u64* __restrict__ ckey,
                                                  u64* __restrict__ top8g,
                                                  float4* __restrict__ top8b, int NROWS) {
  const int lane = threadIdx.x;
  const int row = blockIdx.x;
  const u64* kp = ckey + (size_t)row * CAND;
  u64 k[NSLOT];
#pragma unroll
  for (int s = 0; s < NSLOT; ++s) k[s] = kp[(s << 6) + lane];
  u64 out = 0;
  for (int r = 0; r < TOP8; ++r) {
    u64 lmax = 0;
#pragma unroll
    for (int s = 0; s < NSLOT; ++s) if (k[s] > lmax) lmax = k[s];
    u32 mhi = (u32)(lmax >> 32), mlo = (u32)lmax;
    DPPMAX(0x111); DPPMAX(0x112); DPPMAX(0x114); DPPMAX(0x118); DPPMAX(0x142); DPPMAX(0x143);
    u32 ghi = (u32)__builtin_amdgcn_readlane((int)mhi, 63);
    u32 glo = (u32)__builtin_amdgcn_readlane((int)mlo, 63);
    u64 g = ((u64)ghi << 32) | (u64)glo;
    if (lane == r) out = g;
#pragma unroll
    for (int s = 0; s < NSLOT; ++s) if (k[s] == g) k[s] = 0;   // keys unique per row
  }
  if (lane < TOP8) {
    top8g[(size_t)row * TOP8 + lane] = out;
    int col = (int)(0xFFFFFFFFu - (u32)out);
    top8b[(size_t)row * TOP8 + lane] = out ? pbox[col] : make_float4(0.f, 0.f, 0.f, 0.f);
  }
}

#define RDLF(X, L) __int_as_float(__builtin_amdgcn_readlane(__float_as_int(X), (L)))

// cold stage of row RR (1-based): head = max(top8 minus mask); box from LDS;
// all-owned -> full-pool global fallback.
#define COLD_STAGE(RR) do { \
  u64 kk = 0; float4 kb = zf; \
  if (lane < TOP8) { \
    kk = s_t8[((RR) - 1) * TOP8 + lane]; \
    kb = s_t8b[((RR) - 1) * TOP8 + lane]; \
    u32 cw = 0xFFFFFFFFu - (u32)kk; \
    if (kk && ((s_mask[cw >> 5] >> (cw & 31u)) & 1u)) kk = 0; \
  } \
  u32 mhi = (u32)(kk >> 32), mlo = (u32)kk; \
  DPPMAX(0x111); DPPMAX(0x112); DPPMAX(0x114); \
  u32 ghi = (u32)__builtin_amdgcn_readlane((int)mhi, 7); \
  u32 glo = (u32)__builtin_amdgcn_readlane((int)mlo, 7); \
  head_key = ((u64)ghi << 32) | (u64)glo; \
  if (head_key != 0) { \
    int eL = (int)__ffsll((long long)__ballot(kk == head_key && kk != 0)) - 1; \
    eL = __builtin_amdgcn_readfirstlane(eL); \
    hbox.x = RDLF(kb.x, eL); hbox.y = RDLF(kb.y, eL); \
    hbox.z = RDLF(kb.z, eL); hbox.w = RDLF(kb.w, eL); \
  } else { \
    const u64* kp2 = ckey + (size_t)((RR) - 1) * CAND; \
    u64 lmax = 0; \
    _Pragma("unroll") \
    for (int s = 0; s < NSLOT; ++s) { \
      u64 kf = kp2[(s << 6) + lane]; \
      if (kf) { \
        u32 cw = 0xFFFFFFFFu - (u32)kf; \
        if ((s_mask[cw >> 5] >> (cw & 31u)) & 1u) kf = 0; \
        if (kf > lmax) lmax = kf; \
      } \
    } \
    u32 m2hi = (u32)(lmax >> 32), m2lo = (u32)lmax; \
    { u32 mhi = m2hi, mlo = m2lo; \
      DPPMAX(0x111); DPPMAX(0x112); DPPMAX(0x114); DPPMAX(0x118); DPPMAX(0x142); DPPMAX(0x143); \
      m2hi = (u32)__builtin_amdgcn_readlane((int)mhi, 63); \
      m2lo = (u32)__builtin_amdgcn_readlane((int)mlo, 63); } \
    head_key = ((u64)m2hi << 32) | (u64)m2lo; \
    if (head_key) hbox = pbox[0xFFFFFFFFu - (u32)head_key]; \
  } \
} while (0)

// Kernel B: matcher (wave 0) + fused loss (all 4 waves).
// Matcher: round-9 exact logic; speculative next-row stage overlapped with the
// owned-eval reduce; boxes served from LDS (no per-iteration global loads).
__global__ __launch_bounds__(256, 1) void match_kernel(const float4* __restrict__ pbox,
                                                       const float4* __restrict__ tboxg,
                                                       const u64* __restrict__ ckey,
                                                       const u64* __restrict__ top8g,
                                                       const float4* __restrict__ top8b,
                                                       const float* __restrict__ confs,
                                                       const int* __restrict__ tlab,
                                                       float* __restrict__ out,
                                                       int M, int NROWS, int C) {
  const int tid = threadIdx.x;
  const int lane = tid & 63;
  const int wv = tid >> 6;
  __shared__ u32 s_mask[MASKW];
  __shared__ u64 s_t8[128 * TOP8];
  __shared__ float4 s_t8b[128 * TOP8];
  __shared__ int s_pairs[128];
  __shared__ float s_reg[256];
  __shared__ float s_cls[256];
  __shared__ int   s_acc[256];

  for (int i = tid; i < MASKW; i += 256) s_mask[i] = 0;
  for (int i = tid; i < NROWS * TOP8; i += 256) { s_t8[i] = top8g[i]; s_t8b[i] = top8b[i]; }
  __syncthreads();

  if (wv == 0) {
    float4 zf = make_float4(0.f, 0.f, 0.f, 0.f);
    float4 tbA = (lane < NROWS) ? tboxg[lane] : zf;
    float4 tbB = (lane + 64 < NROWS) ? tboxg[lane + 64] : zf;

    double u_a = 0.0, u_b = 0.0;
    int f_a = 0, f_b = 0;
    int oc0 = -1, orow0 = 0, ovis0 = 0; double ov0 = 0.0; float4 ob0 = zf;
    int oc1 = -1, orow1 = 0, ovis1 = 0; double ov1 = 0.0; float4 ob1 = zf;
    int nown = 0;
    u64 head_key = 0; float4 hbox = zf;
    int row = 1, i0 = 1;
    double u_i0 = 0.0;

    COLD_STAGE(1);
    f_a = (lane == 0); f_b = 0;

    for (int guard = 0; guard < 5000; ++guard) {
      if (head_key == 0) break;                    // unreachable safety

      // ---- speculative stage of row+1 (overlaps with reduce below) ----
      int sr0 = (row < NROWS) ? row : NROWS - 1;   // 0-based next-row index (clamped)
      u64 sk = 0; float4 sbox = zf;
      if (lane < TOP8) {
        sk = s_t8[sr0 * TOP8 + lane];
        sbox = s_t8b[sr0 * TOP8 + lane];
        u32 cw = 0xFFFFFFFFu - (u32)sk;
        if (sk && ((s_mask[cw >> 5] >> (cw & 31u)) & 1u)) sk = 0;
      }

      // ---- owned iou vs current i0 (registers) ----
      int li = (i0 - 1) & 63, hb2 = (i0 - 1) >> 6;
      float tx = RDLF(hb2 ? tbB.x : tbA.x, li);
      float ty = RDLF(hb2 ? tbB.y : tbA.y, li);
      float tz = RDLF(hb2 ? tbB.z : tbA.z, li);
      float tw = RDLF(hb2 ? tbB.w : tbA.w, li);
      float4 tbi = make_float4(tx, ty, tz, tw);
      float ati = (tz - tx) * (tw - ty);

      // ---- owned eval + 3-word DPP min (round-9 exact) ----
      u32 bhi = 0xFFFFFFFFu, blo = 0xFFFFFFFFu; int bcol = 0x7fffffff; int bsl = 15;
      if (oc0 >= 0 && ovis0 != row) {
        float io2 = iou_f32(ob0, tbi, ati);
        double cur = ((-(double)io2) - u_i0) - ov0;
        u64 mk = map_cost(cur);
        bhi = (u32)(mk >> 32); blo = (u32)mk; bcol = oc0; bsl = 6;
      }
      if (oc1 >= 0 && ovis1 != row) {
        float io2 = iou_f32(ob1, tbi, ati);
        double cur = ((-(double)io2) - u_i0) - ov1;
        u64 mk = map_cost(cur);
        u32 hi = (u32)(mk >> 32), lo = (u32)mk;
        bool t = (hi < bhi) || (hi == bhi && ((lo < blo) || (lo == blo && oc1 < bcol)));
        if (t) { bhi = hi; blo = lo; bcol = oc1; bsl = 7; }
      }
      u32 khi = bhi, klo = blo; int kcol = bcol;
      DPP_STEP(0x111); DPP_STEP(0x112); DPP_STEP(0x114); DPP_STEP(0x118);
      DPP_STEP(0x142); DPP_STEP(0x143);
      u32 rhi = (u32)__builtin_amdgcn_readlane((int)khi, 63);
      u32 rlo = (u32)__builtin_amdgcn_readlane((int)klo, 63);
      int rcol = __builtin_amdgcn_readlane(kcol, 63);

      // ---- head cost (fresh best; v==0 exact) ----
      float hio = __uint_as_float((u32)(head_key >> 32));
      int hcol = (int)(0xFFFFFFFFu - (u32)head_key);
      double curh = (-(double)hio) - u_i0;
      u64 mh = map_cost(curh);
      u32 hhi = (u32)(mh >> 32), hlo = (u32)mh;
      bool head_wins = (hhi < rhi) || (hhi == rhi && ((hlo < rlo) || (hlo == rlo && hcol < rcol)));
      const double delta = unmap_cost(head_wins ? mh : (((u64)rhi << 32) | (u64)rlo));

      // ---- updates: u[p[used]] += delta ; v[used] -= delta (pre-append set) ----
      if (f_a) u_a += delta;
      if (f_b) u_b += delta;
      u_i0 += delta;
      if (oc0 >= 0 && ovis0 == row) ov0 -= delta;
      if (oc1 >= 0 && ovis1 == row) ov1 -= delta;

      if (head_wins) {
        const int jc = hcol;
        // finish spec: exact top-2 of next row's masked top8
        u64 k1, k2;
        { u32 mhi = (u32)(sk >> 32), mlo = (u32)sk;
          DPPMAX(0x111); DPPMAX(0x112); DPPMAX(0x114);
          k1 = ((u64)(u32)__builtin_amdgcn_readlane((int)mhi, 7) << 32) |
               (u64)(u32)__builtin_amdgcn_readlane((int)mlo, 7); }
        u64 skz = (sk == k1) ? 0 : sk;
        { u32 mhi = (u32)(skz >> 32), mlo = (u32)skz;
          DPPMAX(0x111); DPPMAX(0x112); DPPMAX(0x114);
          k2 = ((u64)(u32)__builtin_amdgcn_readlane((int)mhi, 7) << 32) |
               (u64)(u32)__builtin_amdgcn_readlane((int)mlo, 7); }
        int e1 = (int)__ffsll((long long)__ballot(sk == k1 && sk != 0)) - 1;
        int e2 = (int)__ffsll((long long)__ballot(skz == k2 && skz != 0)) - 1;
        e1 = __builtin_amdgcn_readfirstlane(e1);
        e2 = __builtin_amdgcn_readfirstlane(e2);
        float4 b1 = zf, b2 = zf;
        if (e1 >= 0) { b1.x = RDLF(sbox.x, e1); b1.y = RDLF(sbox.y, e1);
                       b1.z = RDLF(sbox.z, e1); b1.w = RDLF(sbox.w, e1); }
        if (e2 >= 0) { b2.x = RDLF(sbox.x, e2); b2.y = RDLF(sbox.y, e2);
                       b2.z = RDLF(sbox.z, e2); b2.w = RDLF(sbox.w, e2); }

        // bookkeeping
        if (lane == 0) {
          s_pairs[row - 1] = jc;
          atomicOr(&s_mask[(u32)jc >> 5], 1u << ((u32)jc & 31u));
        }
        {
          int ne = nown, nl = ne & 63, nh = ne >> 6;
          if (lane == nl) {
            if (nh == 0) { oc0 = jc; orow0 = row; ovis0 = 0; ov0 = 0.0; ob0 = hbox; }
            else         { oc1 = jc; orow1 = row; ovis1 = 0; ov1 = 0.0; ob1 = hbox; }
          }
          nown = ne + 1;
        }
        if (row == NROWS) break;
        ++row; i0 = row; u_i0 = 0.0;
        f_a = (lane == ((row - 1) & 63)) && (((row - 1) >> 6) == 0);
        f_b = (lane == ((row - 1) & 63)) && (((row - 1) >> 6) == 1);
        // spec switch: next head = spec1 unless it's the column we just won
        u32 jw = 0xFFFFFFFFu - (u32)jc;
        if ((u32)k1 == jw && k1 != 0) { head_key = k2; hbox = b2; }
        else                          { head_key = k1; hbox = b1; }
        if (head_key == 0) { COLD_STAGE(row); }   // all top8 owned: rare
      } else {
        // ---- chain to owner row (round-9 exact) ----
        bool eq = (bhi == rhi) && (blo == rlo) && (bcol == rcol);
        u64 wm = __ballot(eq);
        int L = (int)__ffsll((long long)wm) - 1;
        L = __builtin_amdgcn_readfirstlane(L);
        int s_w = __builtin_amdgcn_readlane(bsl, L);
        int o = __builtin_amdgcn_readlane((s_w == 6) ? orow0 : orow1, L);
        o = __builtin_amdgcn_readfirstlane(o);
        if (lane == L) { if (s_w == 6) ovis0 = row; else ovis1 = row; }
        int ol = (o - 1) & 63, oh = (o - 1) >> 6;
        if (lane == ol) { if (oh == 0) f_a = 1; else f_b = 1; }
        double uo = oh ? u_b : u_a;
        int uhi2 = __builtin_amdgcn_readlane(__double2hiint(uo), ol);
        int ulo2 = __builtin_amdgcn_readlane(__double2loint(uo), ol);
        u_i0 = __hiloint2double(uhi2, ulo2);
        i0 = o;
        COLD_STAGE(o);
      }
    }
  }
  __syncthreads();

  // ---- fused loss phase (all 256 threads) ----
  float reg = 0.0f, cls = 0.0f; int acc = 0;
  if (tid < NROWS) {
    int pred = s_pairs[tid];
    float4 pb = pbox[pred];
    float4 tb = tboxg[tid];
    float d0 = pb.x - tb.x, d1 = pb.y - tb.y, d2 = pb.z - tb.z, d3 = pb.w - tb.w;
    float a0 = fabsf(d0), a1 = fabsf(d1), a2 = fabsf(d2), a3 = fabsf(d3);
    float s = 0.0f;
    s += (a0 < 1.0f) ? 0.5f * d0 * d0 : a0 - 0.5f;
    s += (a1 < 1.0f) ? 0.5f * d1 * d1 : a1 - 0.5f;
    s += (a2 < 1.0f) ? 0.5f * d2 * d2 : a2 - 0.5f;
    s += (a3 < 1.0f) ? 0.5f * d3 * d3 : a3 - 0.5f;
    reg = s * 0.25f;

    const float* lg = confs + (long long)pred * C;
    float mx = lg[0]; int am = 0;
    for (int k = 1; k < C; ++k) { float x = lg[k]; if (x > mx) { mx = x; am = k; } }
    double se = 0.0;
    for (int k = 0; k < C; ++k) se += exp((double)(lg[k] - mx));
    int lab = tlab[tid];
    double logp = (double)(lg[lab] - mx) - log(se);
    cls = (float)(-logp);
    acc = (am == lab) ? 1 : 0;
  }
  s_reg[tid] = reg; s_cls[tid] = cls; s_acc[tid] = acc;
  __syncthreads();
  for (int s2 = 128; s2 > 0; s2 >>= 1) {
    if (tid < s2) {
      s_reg[tid] += s_reg[tid + s2];
      s_cls[tid] += s_cls[tid + s2];
      s_acc[tid] += s_acc[tid + s2];
    }
    __syncthreads();
  }
  if (tid == 0) {
    out[0] = s_reg[0] + s_cls[0];
    out[1] = (float)s_acc[0];
  }
}

extern "C" void kernel_launch(void* const* d_in, const int* in_sizes, int n_in,
                              void* d_out, int out_size, void* d_ws, size_t ws_size,
                              hipStream_t stream) {
  const float4* pbox  = (const float4*)d_in[0];
  const float*  confs = (const float*)d_in[1];
  const float4* tbox  = (const float4*)d_in[2];
  const int*    tlab  = (const int*)d_in[3];

  int N = in_sizes[0] / 4;          // 100000 predictions (columns)
  int C = in_sizes[1] / N;          // 81 classes
  int NROWS = in_sizes[2] / 4;      // 128 targets (rows), <=128 supported
  int M = N;

  char* w = (char*)d_ws;
  auto alloc = [&](size_t sz) { char* r = w; w += (sz + 255) & ~(size_t)255; return r; };
  u64*    ckey  = (u64*)   alloc((size_t)NROWS * CAND * sizeof(u64));
  u64*    top8g = (u64*)   alloc((size_t)NROWS * TOP8 * sizeof(u64));
  float4* top8b = (float4*)alloc((size_t)NROWS * TOP8 * sizeof(float4));

  select_kernel<<<dim3(SLICES, NROWS), SEL_THR, 0, stream>>>(pbox, tbox, ckey, M, NROWS);
  top8_kernel<<<NROWS, 64, 0, stream>>>(pbox, ckey, top8g, top8b, NROWS);
  match_kernel<<<1, 256, 0, stream>>>(pbox, tbox, ckey, top8g, top8b,
                                      confs, tlab, (float*)d_out, M, NROWS, C);
}

// Round 12
// 227.017 us; speedup vs baseline: 1.2323x; 1.2323x over previous
//
#include <hip/hip_runtime.h>
#include <cstdint>
#include <cstddef>

typedef unsigned long long u64;
typedef unsigned int u32;

#define SLICES 2
#define SCAND 192           // per-slice pool capacity
#define CAND 384            // SLICES * SCAND
#define NSLOT 6             // CAND / 64
#define NBINS 4096
#define SEL_THR 1024
#define SEL_TARGET 128
#define POOLCAP 4096
#define MASKW 3200          // 102400 columns max as bits
#define TOP8 8

// IoU exactly as reference _box_iou, all f32 IEEE ops (bit-exact, absmax=0 rounds 1-11).
__device__ __forceinline__ float iou_f32(float4 p, float4 t, float area_t) {
  float area1 = (p.z - p.x) * (p.w - p.y);
  float ltx = fmaxf(p.x, t.x);
  float lty = fmaxf(p.y, t.y);
  float rbx = fminf(p.z, t.z);
  float rby = fminf(p.w, t.w);
  float wx = fmaxf(rbx - ltx, 0.0f);
  float wy = fmaxf(rby - lty, 0.0f);
  float inter = wx * wy;
  return inter / (area1 + area_t - inter);
}

__device__ __forceinline__ u64 map_cost(double cur) {
  u64 b = (u64)__double_as_longlong(cur);
  if (b == 0x8000000000000000ull) b = 0;                 // canonicalize -0 -> +0
  return (b >> 63) ? ~b : (b | 0x8000000000000000ull);   // order-exact total map
}
__device__ __forceinline__ double unmap_cost(u64 m) {
  u64 b = (m >> 63) ? (m ^ 0x8000000000000000ull) : ~m;
  return __longlong_as_double((long long)b);
}

// Key encoding: (io_bits << 32) | (0xFFFFFFFF - col). Raw u64 max = (io desc, col asc).

// Kernel A: unchanged (proven absmax=0 rounds 8-11).
__global__ __launch_bounds__(SEL_THR) void select_kernel(const float4* __restrict__ pbox,
                                                         const float4* __restrict__ tbox,
                                                         u64* __restrict__ ckey,
                                                         int M, int NROWS) {
  __shared__ u32 s_hist[NBINS];
  __shared__ int s_csum[SEL_THR];
  __shared__ u64 s_pool[POOLCAP];
  __shared__ int s_n, s_n2, s_B;
  const int tid = threadIdx.x;
  const int lane = tid & 63;
  const int slice = blockIdx.x, row = blockIdx.y;
  const int sw = (M + SLICES - 1) / SLICES;
  const int base = slice * sw;
  const int send = min(base + sw, M);
  const float4 tb = tbox[row];
  const float area_t = (tb.z - tb.x) * (tb.w - tb.y);
  u64* orow_key = ckey + (size_t)row * CAND + slice * SCAND;

  for (int b = tid; b < NBINS; b += SEL_THR) s_hist[b] = 0;
  if (tid == 0) { s_n = 0; s_n2 = 0; s_B = 0; }
  __syncthreads();

  const u64 lowmask = (1ull << lane) - 1ull;
  const int iters = (sw + SEL_THR - 1) / SEL_THR;
  for (int it = 0; it < iters; ++it) {
    int j = base + it * SEL_THR + tid;
    bool inr = (j < send);
    float io = -1.0f;
    if (inr) io = iou_f32(pbox[j], tb, area_t);
    bool pos = inr && (io > 0.0f);
    u64 pm = __ballot(pos);
    int wn = (int)__popcll(pm);
    if (wn) {
      int wb = 0;
      if (lane == 0) wb = atomicAdd(&s_n, wn);
      wb = __shfl(wb, 0);
      if (pos) {
        int idx = wb + (int)__popcll(pm & lowmask);
        if (idx < POOLCAP) s_pool[idx] = ((u64)__float_as_uint(io) << 32) | (u64)(0xFFFFFFFFu - (u32)j);
        atomicAdd(&s_hist[__float_as_uint(io) >> 18], 1u);
      }
    }
  }
  __syncthreads();
  const int np = s_n;

  {
    int b0 = tid * 4;
    s_csum[tid] = (int)(s_hist[b0] + s_hist[b0 + 1] + s_hist[b0 + 2] + s_hist[b0 + 3]);
  }
  __syncthreads();

  if (tid < 64) {
    if (np >= SEL_TARGET) {
      int R = 0; bool found = false;
      for (int ch = SEL_THR / 64 - 1; ch >= 0 && !found; --ch) {
        int cum = s_csum[ch * 64 + tid];
        for (int off = 1; off < 64; off <<= 1) {
          int o = __shfl_down(cum, off);
          if (tid + off < 64) cum += o;
        }
        int chunksum = __shfl(cum, 0);
        if (R + chunksum >= SEL_TARGET) {
          u64 m = __ballot(R + cum >= SEL_TARGET);
          int l = 63 - __clzll(m);
          int R2 = R + ((l < 63) ? __shfl(cum, l + 1) : 0);
          if (tid == 0) {
            int bb = (ch * 64 + l) * 4;
            int B2 = bb;
            for (int b = bb + 3; b >= bb; --b) {
              R2 += (int)s_hist[b];
              if (R2 >= SEL_TARGET) { B2 = b; break; }
            }
            s_B = B2;
          }
          found = true;
        } else R += chunksum;
      }
    }
  }
  __syncthreads();
  const int B = s_B;

  if (np >= SEL_TARGET) {
    if (np <= POOLCAP) {
      for (int t = tid; t < np; t += SEL_THR) {
        u64 k = s_pool[t];
        if ((u32)(k >> 50) >= (u32)B) {
          int pos = atomicAdd(&s_n2, 1);
          if (pos < SCAND) orow_key[pos] = k;
        }
      }
    } else {
      for (int j = base + tid; j < send; j += SEL_THR) {
        float io = iou_f32(pbox[j], tb, area_t);
        if (io > 0.0f && (int)(__float_as_uint(io) >> 18) >= B) {
          int pos = atomicAdd(&s_n2, 1);
          if (pos < SCAND) orow_key[pos] = ((u64)__float_as_uint(io) << 32) | (u64)(0xFFFFFFFFu - (u32)j);
        }
      }
    }
    __syncthreads();
  } else {
    for (int t = tid; t < np; t += SEL_THR) {
      u64 k = s_pool[t];
      int pos = atomicAdd(&s_n2, 1);
      if (pos < SCAND) orow_key[pos] = k;
    }
    __syncthreads();
    if (tid < 64) {
      int need = SEL_TARGET - np, got = 0;
      int base_n = s_n2;
      for (int b2 = base; b2 < send && got < need; b2 += 64) {
        int j = b2 + tid;
        float io = (j < send) ? iou_f32(pbox[j], tb, area_t) : -1.0f;
        bool z = (j < send) && (io == 0.0f);
        u64 zm = __ballot(z);
        int rank = (int)__popcll(zm & ((1ull << tid) - 1ull));
        if (z && rank < need - got) {
          int pos = base_n + got + rank;
          if (pos < SCAND) orow_key[pos] = (u64)(0xFFFFFFFFu - (u32)j);
        }
        int zn = (int)__popcll(zm); if (zn > need - got) zn = need - got;
        got += zn;
      }
      if (tid == 0) s_n2 = base_n + got;
    }
    __syncthreads();
  }
  int n = min(s_n2, SCAND);
  for (int t2 = n + tid; t2 < SCAND; t2 += SEL_THR) orow_key[t2] = 0ull;
}

// max DPP step (identity: 0)
#define DPPMAX(CTRL) do { \
  u32 oh2 = (u32)__builtin_amdgcn_update_dpp(0, (int)mhi, (CTRL), 0xF, 0xF, false); \
  u32 ol2 = (u32)__builtin_amdgcn_update_dpp(0, (int)mlo, (CTRL), 0xF, 0xF, false); \
  bool gt = (oh2 > mhi) || (oh2 == mhi && ol2 > mlo); \
  if (gt) { mhi = oh2; mlo = ol2; } \
} while (0)

// 2-word u64 min step (identity: ~0)
#define DPPMIN2(CTRL) do { \
  u32 ohi = (u32)__builtin_amdgcn_update_dpp((int)0xFFFFFFFF, (int)khi, (CTRL), 0xF, 0xF, false); \
  u32 olo = (u32)__builtin_amdgcn_update_dpp((int)0xFFFFFFFF, (int)klo, (CTRL), 0xF, 0xF, false); \
  bool lt = (ohi < khi) || (ohi == khi && olo < klo); \
  if (lt) { khi = ohi; klo = olo; } \
} while (0)

// 1-word i32 min step (identity: INT_MAX)
#define DPPMINC(CTRL) do { \
  int occ = __builtin_amdgcn_update_dpp((int)0x7FFFFFFF, cc, (CTRL), 0xF, 0xF, false); \
  if (occ < cc) cc = occ; \
} while (0)

// Kernel A2: exact top-8 of each row's pool by u64 key + candidate boxes (proven).
__global__ __launch_bounds__(64) void top8_kernel(const float4* __restrict__ pbox,
                                                  const u64* __restrict__ ckey,
                                                  u64* __restrict__ top8g,
                                                  float4* __restrict__ top8b, int NROWS) {
  const int lane = threadIdx.x;
  const int row = blockIdx.x;
  const u64* kp = ckey + (size_t)row * CAND;
  u64 k[NSLOT];
#pragma unroll
  for (int s = 0; s < NSLOT; ++s) k[s] = kp[(s << 6) + lane];
  u64 out = 0;
  for (int r = 0; r < TOP8; ++r) {
    u64 lmax = 0;
#pragma unroll
    for (int s = 0; s < NSLOT; ++s) if (k[s] > lmax) lmax = k[s];
    u32 mhi = (u32)(lmax >> 32), mlo = (u32)lmax;
    DPPMAX(0x111); DPPMAX(0x112); DPPMAX(0x114); DPPMAX(0x118); DPPMAX(0x142); DPPMAX(0x143);
    u32 ghi = (u32)__builtin_amdgcn_readlane((int)mhi, 63);
    u32 glo = (u32)__builtin_amdgcn_readlane((int)mlo, 63);
    u64 g = ((u64)ghi << 32) | (u64)glo;
    if (lane == r) out = g;
#pragma unroll
    for (int s = 0; s < NSLOT; ++s) if (k[s] == g) k[s] = 0;   // keys unique per row
  }
  if (lane < TOP8) {
    top8g[(size_t)row * TOP8 + lane] = out;
    int col = (int)(0xFFFFFFFFu - (u32)out);
    top8b[(size_t)row * TOP8 + lane] = out ? pbox[col] : make_float4(0.f, 0.f, 0.f, 0.f);
  }
}

#define RDLF(X, L) __int_as_float(__builtin_amdgcn_readlane(__float_as_int(X), (L)))

// Kernel B: matcher (wave 0, persistent register head cache) + fused loss (4 waves).
// Heads: lane l holds head keys of rows l and l+64 (h0,h1) = max over pool minus
// owned; maintained incrementally at augments (ownership frozen during searches).
// Invariants: visited => owned; v!=0 => owned.
__global__ __launch_bounds__(256, 1) void match_kernel(const float4* __restrict__ pbox,
                                                       const float4* __restrict__ tboxg,
                                                       const u64* __restrict__ ckey,
                                                       const u64* __restrict__ top8g,
                                                       const float4* __restrict__ top8b,
                                                       const float* __restrict__ confs,
                                                       const int* __restrict__ tlab,
                                                       float* __restrict__ out,
                                                       int M, int NROWS, int C) {
  const int tid = threadIdx.x;
  const int lane = tid & 63;
  const int wv = tid >> 6;
  __shared__ u32 s_mask[MASKW];
  __shared__ u64 s_t8[128 * TOP8];
  __shared__ float4 s_t8b[128 * TOP8];
  __shared__ int s_pairs[128];
  __shared__ float s_reg[256];
  __shared__ float s_cls[256];
  __shared__ int   s_acc[256];

  for (int i = tid; i < MASKW; i += 256) s_mask[i] = 0;
  for (int i = tid; i < NROWS * TOP8; i += 256) { s_t8[i] = top8g[i]; s_t8b[i] = top8b[i]; }
  __syncthreads();

  if (wv == 0) {
    float4 zf = make_float4(0.f, 0.f, 0.f, 0.f);
    float4 tbA = (lane < NROWS) ? tboxg[lane] : zf;
    float4 tbB = (lane + 64 < NROWS) ? tboxg[lane + 64] : zf;

    double u_a = 0.0, u_b = 0.0;
    int f_a = 0, f_b = 0;
    int oc0 = -1, orow0 = 0, ovis0 = 0; double ov0 = 0.0; float4 ob0 = zf;
    int oc1 = -1, orow1 = 0, ovis1 = 0; double ov1 = 0.0; float4 ob1 = zf;
    int nown = 0;
    u64 h0 = (lane < NROWS) ? s_t8[lane * TOP8] : 0;          // head of row lane+1
    u64 h1 = (lane + 64 < NROWS) ? s_t8[(lane + 64) * TOP8] : 0;
    int p0 = 0, p1 = 0;
    int row = 1, i0 = 1;
    double u_i0 = 0.0;
    f_a = (lane == 0); f_b = 0;

    for (int guard = 0; guard < 8000; ++guard) {
      // ---- broadcast target box + head key of i0 (registers only) ----
      int li = (i0 - 1) & 63, hb = (i0 - 1) >> 6;
      float tx = RDLF(hb ? tbB.x : tbA.x, li);
      float ty = RDLF(hb ? tbB.y : tbA.y, li);
      float tz = RDLF(hb ? tbB.z : tbA.z, li);
      float tw = RDLF(hb ? tbB.w : tbA.w, li);
      u64 hsel = hb ? h1 : h0;
      u32 hh = (u32)__builtin_amdgcn_readlane((int)(u32)(hsel >> 32), li);
      u32 hl = (u32)__builtin_amdgcn_readlane((int)(u32)hsel, li);
      u64 head_key = ((u64)hh << 32) | (u64)hl;
      if (head_key == 0) break;                   // unreachable safety

      float4 tbi = make_float4(tx, ty, tz, tw);
      float ati = (tz - tx) * (tw - ty);

      // ---- owned eval (registers) ----
      u32 bhi = 0xFFFFFFFFu, blo = 0xFFFFFFFFu; int bcol = 0x7fffffff; int bsl = 15;
      if (oc0 >= 0 && ovis0 != row) {
        float io2 = iou_f32(ob0, tbi, ati);
        double cur = ((-(double)io2) - u_i0) - ov0;   // exact reference f64 op order
        u64 mk = map_cost(cur);
        bhi = (u32)(mk >> 32); blo = (u32)mk; bcol = oc0; bsl = 6;
      }
      if (oc1 >= 0 && ovis1 != row) {
        float io2 = iou_f32(ob1, tbi, ati);
        double cur = ((-(double)io2) - u_i0) - ov1;
        u64 mk = map_cost(cur);
        u32 hi = (u32)(mk >> 32), lo = (u32)mk;
        bool t = (hi < bhi) || (hi == bhi && ((lo < blo) || (lo == blo && oc1 < bcol)));
        if (t) { bhi = hi; blo = lo; bcol = oc1; bsl = 7; }
      }
      // ---- 2-word DPP min; col tie-break on rare uniform branch ----
      u32 khi = bhi, klo = blo;
      DPPMIN2(0x111); DPPMIN2(0x112); DPPMIN2(0x114); DPPMIN2(0x118);
      DPPMIN2(0x142); DPPMIN2(0x143);
      u32 rhi = (u32)__builtin_amdgcn_readlane((int)khi, 63);
      u32 rlo = (u32)__builtin_amdgcn_readlane((int)klo, 63);
      bool eq = (bhi == rhi) && (blo == rlo);
      u64 wm = __ballot(eq);
      int L, rcol;
      if (__popcll(wm) == 1) {
        L = (int)__ffsll((long long)wm) - 1;
        L = __builtin_amdgcn_readfirstlane(L);
        rcol = __builtin_amdgcn_readlane(bcol, L);
      } else {                                    // rare: exact col tie or no-owned
        int cc = eq ? bcol : 0x7fffffff;
        DPPMINC(0x111); DPPMINC(0x112); DPPMINC(0x114); DPPMINC(0x118);
        DPPMINC(0x142); DPPMINC(0x143);
        rcol = __builtin_amdgcn_readlane(cc, 63);
        L = (int)__ffsll((long long)__ballot(eq && bcol == rcol)) - 1;
        L = __builtin_amdgcn_readfirstlane(L);
      }

      // ---- head cost (fresh best; v==0 exact) ----
      float hio = __uint_as_float((u32)(head_key >> 32));
      int hcol = (int)(0xFFFFFFFFu - (u32)head_key);
      double curh = (-(double)hio) - u_i0;          // == ((-io)-u)-0.0 bitwise
      u64 mhc = map_cost(curh);
      u32 hhi = (u32)(mhc >> 32), hlo = (u32)mhc;
      bool head_wins = (hhi < rhi) || (hhi == rhi && ((hlo < rlo) || (hlo == rlo && hcol < rcol)));
      const double delta = unmap_cost(head_wins ? mhc : (((u64)rhi << 32) | (u64)rlo));

      // ---- updates: u[p[used]] += delta ; v[used] -= delta (pre-append set) ----
      if (f_a) u_a += delta;
      if (f_b) u_b += delta;
      u_i0 += delta;
      if (oc0 >= 0 && ovis0 == row) ov0 -= delta;
      if (oc1 >= 0 && ovis1 == row) ov1 -= delta;

      if (head_wins) {
        const int jc = hcol;
        if (lane == 0) {
          s_pairs[row - 1] = jc;
          atomicOr(&s_mask[(u32)jc >> 5], 1u << ((u32)jc & 31u));
        }
        if (row == NROWS) break;
        // winner box (read BEFORE walks move the winner's ptr)
        int wl = (row - 1) & 63, ws = (row - 1) >> 6;
        int pw = __builtin_amdgcn_readlane(ws ? p1 : p0, wl);
        float4 hbox;
        if (pw < TOP8) {
          float4 wbl = zf;
          if (lane == wl) wbl = s_t8b[(row - 1) * TOP8 + pw];
          hbox.x = RDLF(wbl.x, wl); hbox.y = RDLF(wbl.y, wl);
          hbox.z = RDLF(wbl.z, wl); hbox.w = RDLF(wbl.w, wl);
        } else {
          hbox = pbox[jc];                        // fallback-headed winner (rare)
        }
        asm volatile("s_waitcnt lgkmcnt(0)" ::: "memory");  // mask visible to walks
        // ---- advance heads whose col == jc (few lanes; walk sorted top8) ----
        u32 jw = (u32)jc;
        bool adv0 = h0 && ((0xFFFFFFFFu - (u32)h0) == jw);
        if (adv0) {
          int p = p0; u64 k;
          for (;;) {
            ++p;
            k = (p < TOP8) ? s_t8[lane * TOP8 + p] : 0;
            if (!k) break;
            u32 c = 0xFFFFFFFFu - (u32)k;
            if (!((s_mask[c >> 5] >> (c & 31u)) & 1u)) break;
          }
          h0 = k; p0 = p;
        }
        bool adv1 = h1 && ((0xFFFFFFFFu - (u32)h1) == jw);
        if (adv1) {
          int p = p1; u64 k;
          for (;;) {
            ++p;
            k = (p < TOP8) ? s_t8[(lane + 64) * TOP8 + p] : 0;
            if (!k) break;
            u32 c = 0xFFFFFFFFu - (u32)k;
            if (!((s_mask[c >> 5] >> (c & 31u)) & 1u)) break;
          }
          h1 = k; p1 = p;
        }
        // ---- rare fallback: a row exhausted its top8 -> full-pool scan ----
        u64 fb0 = __ballot(adv0 && h0 == 0);
        u64 fb1 = __ballot(adv1 && h1 == 0);
        while (fb0 | fb1) {
          bool s1 = (fb0 == 0);
          u64 mcur = s1 ? fb1 : fb0;
          int L2 = (int)__ffsll((long long)mcur) - 1;
          L2 = __builtin_amdgcn_readfirstlane(L2);
          int rw = L2 + (s1 ? 64 : 0);
          const u64* kp2 = ckey + (size_t)rw * CAND;
          u64 lmax = 0;
#pragma unroll
          for (int s2 = 0; s2 < NSLOT; ++s2) {
            u64 kf = kp2[(s2 << 6) + lane];
            if (kf) {
              u32 c = 0xFFFFFFFFu - (u32)kf;
              if ((s_mask[c >> 5] >> (c & 31u)) & 1u) kf = 0;
              if (kf > lmax) lmax = kf;
            }
          }
          u32 mhi = (u32)(lmax >> 32), mlo = (u32)lmax;
          DPPMAX(0x111); DPPMAX(0x112); DPPMAX(0x114); DPPMAX(0x118);
          DPPMAX(0x142); DPPMAX(0x143);
          u32 g2hi = (u32)__builtin_amdgcn_readlane((int)mhi, 63);
          u32 g2lo = (u32)__builtin_amdgcn_readlane((int)mlo, 63);
          u64 g = ((u64)g2hi << 32) | (u64)g2lo;
          if (lane == L2) { if (s1) { h1 = g; p1 = TOP8; } else { h0 = g; p0 = TOP8; } }
          if (s1) fb1 &= fb1 - 1; else fb0 &= fb0 - 1;
        }
        // ---- insert owned slot ----
        {
          int nl = nown & 63, nh = nown >> 6;
          if (lane == nl) {
            if (nh == 0) { oc0 = jc; orow0 = row; ovis0 = 0; ov0 = 0.0; ob0 = hbox; }
            else         { oc1 = jc; orow1 = row; ovis1 = 0; ov1 = 0.0; ob1 = hbox; }
          }
          ++nown;
        }
        ++row; i0 = row; u_i0 = 0.0;
        f_a = (lane == ((row - 1) & 63)) && (((row - 1) >> 6) == 0);
        f_b = (lane == ((row - 1) & 63)) && (((row - 1) >> 6) == 1);
      } else {
        // ---- chain to owner row: registers + readlanes only ----
        int s_w = __builtin_amdgcn_readlane(bsl, L);
        int o = __builtin_amdgcn_readlane((s_w == 6) ? orow0 : orow1, L);
        o = __builtin_amdgcn_readfirstlane(o);
        if (lane == L) { if (s_w == 6) ovis0 = row; else ovis1 = row; }
        int ol = (o - 1) & 63, oh = (o - 1) >> 6;
        if (lane == ol) { if (oh == 0) f_a = 1; else f_b = 1; }
        double uo = oh ? u_b : u_a;
        int uhi2 = __builtin_amdgcn_readlane(__double2hiint(uo), ol);
        int ulo2 = __builtin_amdgcn_readlane(__double2loint(uo), ol);
        u_i0 = __hiloint2double(uhi2, ulo2);
        i0 = o;
      }
    }
  }
  __syncthreads();

  // ---- fused loss phase (all 256 threads) ----
  float reg = 0.0f, cls = 0.0f; int acc = 0;
  if (tid < NROWS) {
    int pred = s_pairs[tid];
    float4 pb = pbox[pred];
    float4 tb = tboxg[tid];
    float d0 = pb.x - tb.x, d1 = pb.y - tb.y, d2 = pb.z - tb.z, d3 = pb.w - tb.w;
    float a0 = fabsf(d0), a1 = fabsf(d1), a2 = fabsf(d2), a3 = fabsf(d3);
    float s = 0.0f;
    s += (a0 < 1.0f) ? 0.5f * d0 * d0 : a0 - 0.5f;
    s += (a1 < 1.0f) ? 0.5f * d1 * d1 : a1 - 0.5f;
    s += (a2 < 1.0f) ? 0.5f * d2 * d2 : a2 - 0.5f;
    s += (a3 < 1.0f) ? 0.5f * d3 * d3 : a3 - 0.5f;
    reg = s * 0.25f;

    const float* lg = confs + (long long)pred * C;
    float mx = lg[0]; int am = 0;
    for (int k = 1; k < C; ++k) { float x = lg[k]; if (x > mx) { mx = x; am = k; } }
    double se = 0.0;
    for (int k = 0; k < C; ++k) se += exp((double)(lg[k] - mx));
    int lab = tlab[tid];
    double logp = (double)(lg[lab] - mx) - log(se);
    cls = (float)(-logp);
    acc = (am == lab) ? 1 : 0;
  }
  s_reg[tid] = reg; s_cls[tid] = cls; s_acc[tid] = acc;
  __syncthreads();
  for (int s2 = 128; s2 > 0; s2 >>= 1) {
    if (tid < s2) {
      s_reg[tid] += s_reg[tid + s2];
      s_cls[tid] += s_cls[tid + s2];
      s_acc[tid] += s_acc[tid + s2];
    }
    __syncthreads();
  }
  if (tid == 0) {
    out[0] = s_reg[0] + s_cls[0];
    out[1] = (float)s_acc[0];
  }
}

extern "C" void kernel_launch(void* const* d_in, const int* in_sizes, int n_in,
                              void* d_out, int out_size, void* d_ws, size_t ws_size,
                              hipStream_t stream) {
  const float4* pbox  = (const float4*)d_in[0];
  const float*  confs = (const float*)d_in[1];
  const float4* tbox  = (const float4*)d_in[2];
  const int*    tlab  = (const int*)d_in[3];

  int N = in_sizes[0] / 4;          // 100000 predictions (columns)
  int C = in_sizes[1] / N;          // 81 classes
  int NROWS = in_sizes[2] / 4;      // 128 targets (rows), <=128 supported
  int M = N;

  char* w = (char*)d_ws;
  auto alloc = [&](size_t sz) { char* r = w; w += (sz + 255) & ~(size_t)255; return r; };
  u64*    ckey  = (u64*)   alloc((size_t)NROWS * CAND * sizeof(u64));
  u64*    top8g = (u64*)   alloc((size_t)NROWS * TOP8 * sizeof(u64));
  float4* top8b = (float4*)alloc((size_t)NROWS * TOP8 * sizeof(float4));

  select_kernel<<<dim3(SLICES, NROWS), SEL_THR, 0, stream>>>(pbox, tbox, ckey, M, NROWS);
  top8_kernel<<<NROWS, 64, 0, stream>>>(pbox, ckey, top8g, top8b, NROWS);
  match_kernel<<<1, 256, 0, stream>>>(pbox, tbox, ckey, top8g, top8b,
                                      confs, tlab, (float*)d_out, M, NROWS, C);
}

// Round 13
// 214.746 us; speedup vs baseline: 1.3027x; 1.0571x over previous
//
#include <hip/hip_runtime.h>
#include <cstdint>
#include <cstddef>

typedef unsigned long long u64;
typedef unsigned int u32;

#define SLICES 2
#define SCAND 192           // per-slice pool capacity
#define CAND 384            // SLICES * SCAND
#define NSLOT 6             // CAND / 64
#define NBINS 4096
#define SEL_THR 1024
#define SEL_TARGET 128
#define POOLCAP 4096
#define MASKW 3200          // 102400 columns max as bits
#define TOP8 8

// IoU exactly as reference _box_iou, all f32 IEEE ops (bit-exact, absmax=0 rounds 1-12).
__device__ __forceinline__ float iou_f32(float4 p, float4 t, float area_t) {
  float area1 = (p.z - p.x) * (p.w - p.y);
  float ltx = fmaxf(p.x, t.x);
  float lty = fmaxf(p.y, t.y);
  float rbx = fminf(p.z, t.z);
  float rby = fminf(p.w, t.w);
  float wx = fmaxf(rbx - ltx, 0.0f);
  float wy = fmaxf(rby - lty, 0.0f);
  float inter = wx * wy;
  return inter / (area1 + area_t - inter);
}

__device__ __forceinline__ u64 map_cost(double cur) {
  u64 b = (u64)__double_as_longlong(cur);
  if (b == 0x8000000000000000ull) b = 0;                 // canonicalize -0 -> +0
  return (b >> 63) ? ~b : (b | 0x8000000000000000ull);   // order-exact total map
}
__device__ __forceinline__ double unmap_cost(u64 m) {
  u64 b = (m >> 63) ? (m ^ 0x8000000000000000ull) : ~m;
  return __longlong_as_double((long long)b);
}

// Key encoding: (io_bits << 32) | (0xFFFFFFFF - col). Raw u64 max = (io desc, col asc).

// Kernel A: unchanged (proven absmax=0 rounds 8-12).
__global__ __launch_bounds__(SEL_THR) void select_kernel(const float4* __restrict__ pbox,
                                                         const float4* __restrict__ tbox,
                                                         u64* __restrict__ ckey,
                                                         int M, int NROWS) {
  __shared__ u32 s_hist[NBINS];
  __shared__ int s_csum[SEL_THR];
  __shared__ u64 s_pool[POOLCAP];
  __shared__ int s_n, s_n2, s_B;
  const int tid = threadIdx.x;
  const int lane = tid & 63;
  const int slice = blockIdx.x, row = blockIdx.y;
  const int sw = (M + SLICES - 1) / SLICES;
  const int base = slice * sw;
  const int send = min(base + sw, M);
  const float4 tb = tbox[row];
  const float area_t = (tb.z - tb.x) * (tb.w - tb.y);
  u64* orow_key = ckey + (size_t)row * CAND + slice * SCAND;

  for (int b = tid; b < NBINS; b += SEL_THR) s_hist[b] = 0;
  if (tid == 0) { s_n = 0; s_n2 = 0; s_B = 0; }
  __syncthreads();

  const u64 lowmask = (1ull << lane) - 1ull;
  const int iters = (sw + SEL_THR - 1) / SEL_THR;
  for (int it = 0; it < iters; ++it) {
    int j = base + it * SEL_THR + tid;
    bool inr = (j < send);
    float io = -1.0f;
    if (inr) io = iou_f32(pbox[j], tb, area_t);
    bool pos = inr && (io > 0.0f);
    u64 pm = __ballot(pos);
    int wn = (int)__popcll(pm);
    if (wn) {
      int wb = 0;
      if (lane == 0) wb = atomicAdd(&s_n, wn);
      wb = __shfl(wb, 0);
      if (pos) {
        int idx = wb + (int)__popcll(pm & lowmask);
        if (idx < POOLCAP) s_pool[idx] = ((u64)__float_as_uint(io) << 32) | (u64)(0xFFFFFFFFu - (u32)j);
        atomicAdd(&s_hist[__float_as_uint(io) >> 18], 1u);
      }
    }
  }
  __syncthreads();
  const int np = s_n;

  {
    int b0 = tid * 4;
    s_csum[tid] = (int)(s_hist[b0] + s_hist[b0 + 1] + s_hist[b0 + 2] + s_hist[b0 + 3]);
  }
  __syncthreads();

  if (tid < 64) {
    if (np >= SEL_TARGET) {
      int R = 0; bool found = false;
      for (int ch = SEL_THR / 64 - 1; ch >= 0 && !found; --ch) {
        int cum = s_csum[ch * 64 + tid];
        for (int off = 1; off < 64; off <<= 1) {
          int o = __shfl_down(cum, off);
          if (tid + off < 64) cum += o;
        }
        int chunksum = __shfl(cum, 0);
        if (R + chunksum >= SEL_TARGET) {
          u64 m = __ballot(R + cum >= SEL_TARGET);
          int l = 63 - __clzll(m);
          int R2 = R + ((l < 63) ? __shfl(cum, l + 1) : 0);
          if (tid == 0) {
            int bb = (ch * 64 + l) * 4;
            int B2 = bb;
            for (int b = bb + 3; b >= bb; --b) {
              R2 += (int)s_hist[b];
              if (R2 >= SEL_TARGET) { B2 = b; break; }
            }
            s_B = B2;
          }
          found = true;
        } else R += chunksum;
      }
    }
  }
  __syncthreads();
  const int B = s_B;

  if (np >= SEL_TARGET) {
    if (np <= POOLCAP) {
      for (int t = tid; t < np; t += SEL_THR) {
        u64 k = s_pool[t];
        if ((u32)(k >> 50) >= (u32)B) {
          int pos = atomicAdd(&s_n2, 1);
          if (pos < SCAND) orow_key[pos] = k;
        }
      }
    } else {
      for (int j = base + tid; j < send; j += SEL_THR) {
        float io = iou_f32(pbox[j], tb, area_t);
        if (io > 0.0f && (int)(__float_as_uint(io) >> 18) >= B) {
          int pos = atomicAdd(&s_n2, 1);
          if (pos < SCAND) orow_key[pos] = ((u64)__float_as_uint(io) << 32) | (u64)(0xFFFFFFFFu - (u32)j);
        }
      }
    }
    __syncthreads();
  } else {
    for (int t = tid; t < np; t += SEL_THR) {
      u64 k = s_pool[t];
      int pos = atomicAdd(&s_n2, 1);
      if (pos < SCAND) orow_key[pos] = k;
    }
    __syncthreads();
    if (tid < 64) {
      int need = SEL_TARGET - np, got = 0;
      int base_n = s_n2;
      for (int b2 = base; b2 < send && got < need; b2 += 64) {
        int j = b2 + tid;
        float io = (j < send) ? iou_f32(pbox[j], tb, area_t) : -1.0f;
        bool z = (j < send) && (io == 0.0f);
        u64 zm = __ballot(z);
        int rank = (int)__popcll(zm & ((1ull << tid) - 1ull));
        if (z && rank < need - got) {
          int pos = base_n + got + rank;
          if (pos < SCAND) orow_key[pos] = (u64)(0xFFFFFFFFu - (u32)j);
        }
        int zn = (int)__popcll(zm); if (zn > need - got) zn = need - got;
        got += zn;
      }
      if (tid == 0) s_n2 = base_n + got;
    }
    __syncthreads();
  }
  int n = min(s_n2, SCAND);
  for (int t2 = n + tid; t2 < SCAND; t2 += SEL_THR) orow_key[t2] = 0ull;
}

// max DPP step (identity: 0)
#define DPPMAX(CTRL) do { \
  u32 oh2 = (u32)__builtin_amdgcn_update_dpp(0, (int)mhi, (CTRL), 0xF, 0xF, false); \
  u32 ol2 = (u32)__builtin_amdgcn_update_dpp(0, (int)mlo, (CTRL), 0xF, 0xF, false); \
  bool gt = (oh2 > mhi) || (oh2 == mhi && ol2 > mlo); \
  if (gt) { mhi = oh2; mlo = ol2; } \
} while (0)

// 1-word u32 min step (identity: ~0)
#define DPPMINH(CTRL) do { \
  u32 ohi = (u32)__builtin_amdgcn_update_dpp((int)0xFFFFFFFF, (int)khi, (CTRL), 0xF, 0xF, false); \
  if (ohi < khi) khi = ohi; \
} while (0)

#define DPPMINL(CTRL) do { \
  u32 olo = (u32)__builtin_amdgcn_update_dpp((int)0xFFFFFFFF, (int)klo2, (CTRL), 0xF, 0xF, false); \
  if (olo < klo2) klo2 = olo; \
} while (0)

#define DPPMINC(CTRL) do { \
  int occ = __builtin_amdgcn_update_dpp((int)0x7FFFFFFF, cc, (CTRL), 0xF, 0xF, false); \
  if (occ < cc) cc = occ; \
} while (0)

// Kernel A2: exact top-8 of each row's pool by u64 key + candidate boxes (proven).
__global__ __launch_bounds__(64) void top8_kernel(const float4* __restrict__ pbox,
                                                  const u64* __restrict__ ckey,
                                                  u64* __restrict__ top8g,
                                                  float4* __restrict__ top8b, int NROWS) {
  const int lane = threadIdx.x;
  const int row = blockIdx.x;
  const u64* kp = ckey + (size_t)row * CAND;
  u64 k[NSLOT];
#pragma unroll
  for (int s = 0; s < NSLOT; ++s) k[s] = kp[(s << 6) + lane];
  u64 out = 0;
  for (int r = 0; r < TOP8; ++r) {
    u64 lmax = 0;
#pragma unroll
    for (int s = 0; s < NSLOT; ++s) if (k[s] > lmax) lmax = k[s];
    u32 mhi = (u32)(lmax >> 32), mlo = (u32)lmax;
    DPPMAX(0x111); DPPMAX(0x112); DPPMAX(0x114); DPPMAX(0x118); DPPMAX(0x142); DPPMAX(0x143);
    u32 ghi = (u32)__builtin_amdgcn_readlane((int)mhi, 63);
    u32 glo = (u32)__builtin_amdgcn_readlane((int)mlo, 63);
    u64 g = ((u64)ghi << 32) | (u64)glo;
    if (lane == r) out = g;
#pragma unroll
    for (int s = 0; s < NSLOT; ++s) if (k[s] == g) k[s] = 0;   // keys unique per row
  }
  if (lane < TOP8) {
    top8g[(size_t)row * TOP8 + lane] = out;
    int col = (int)(0xFFFFFFFFu - (u32)out);
    top8b[(size_t)row * TOP8 + lane] = out ? pbox[col] : make_float4(0.f, 0.f, 0.f, 0.f);
  }
}

#define RDLF(X, L) __int_as_float(__builtin_amdgcn_readlane(__float_as_int(X), (L)))

// Kernel B: matcher (wave 0, persistent register head cache) + fused loss (4 waves).
// Heads: lane l holds head keys of rows l and l+64 (h0,h1) = max over pool minus
// owned; maintained incrementally at augments (ownership frozen during searches).
// Invariants: visited => owned; v!=0 => owned.
__global__ __launch_bounds__(256, 1) void match_kernel(const float4* __restrict__ pbox,
                                                       const float4* __restrict__ tboxg,
                                                       const u64* __restrict__ ckey,
                                                       const u64* __restrict__ top8g,
                                                       const float4* __restrict__ top8b,
                                                       const float* __restrict__ confs,
                                                       const int* __restrict__ tlab,
                                                       float* __restrict__ out,
                                                       int M, int NROWS, int C) {
  const int tid = threadIdx.x;
  const int lane = tid & 63;
  const int wv = tid >> 6;
  __shared__ u32 s_mask[MASKW];
  __shared__ u64 s_t8[128 * TOP8];
  __shared__ float4 s_t8b[128 * TOP8];
  __shared__ int s_pairs[128];
  __shared__ float s_reg[256];
  __shared__ float s_cls[256];
  __shared__ int   s_acc[256];

  for (int i = tid; i < MASKW; i += 256) s_mask[i] = 0;
  for (int i = tid; i < NROWS * TOP8; i += 256) { s_t8[i] = top8g[i]; s_t8b[i] = top8b[i]; }
  __syncthreads();

  if (wv == 0) {
    float4 zf = make_float4(0.f, 0.f, 0.f, 0.f);
    float4 tbA = (lane < NROWS) ? tboxg[lane] : zf;
    float4 tbB = (lane + 64 < NROWS) ? tboxg[lane + 64] : zf;

    double u_a = 0.0, u_b = 0.0;
    int f_a = 0, f_b = 0;
    int oc0 = -1, orow0 = 0, ovis0 = 0; double ov0 = 0.0; float4 ob0 = zf;
    int oc1 = -1, orow1 = 0, ovis1 = 0; double ov1 = 0.0; float4 ob1 = zf;
    int nown = 0;
    u64 h0 = (lane < NROWS) ? s_t8[lane * TOP8] : 0;          // head of row lane+1
    u64 h1 = (lane + 64 < NROWS) ? s_t8[(lane + 64) * TOP8] : 0;
    int p0 = 0, p1 = 0;
    int row = 1, i0 = 1;
    double u_i0 = 0.0;
    f_a = (lane == 0); f_b = 0;

    for (int guard = 0; guard < 8000; ++guard) {
      // ---- broadcast target box + head key of i0 (registers only) ----
      int li = (i0 - 1) & 63, hb = (i0 - 1) >> 6;
      float tx = RDLF(hb ? tbB.x : tbA.x, li);
      float ty = RDLF(hb ? tbB.y : tbA.y, li);
      float tz = RDLF(hb ? tbB.z : tbA.z, li);
      float tw = RDLF(hb ? tbB.w : tbA.w, li);
      u64 hsel = hb ? h1 : h0;
      u32 hh = (u32)__builtin_amdgcn_readlane((int)(u32)(hsel >> 32), li);
      u32 hl = (u32)__builtin_amdgcn_readlane((int)(u32)hsel, li);
      u64 head_key = ((u64)hh << 32) | (u64)hl;
      if (head_key == 0) break;                   // unreachable safety

      float4 tbi = make_float4(tx, ty, tz, tw);
      float ati = (tz - tx) * (tw - ty);

      // ---- owned eval (registers) ----
      u32 bhi = 0xFFFFFFFFu, blo = 0xFFFFFFFFu; int bcol = 0x7fffffff; int bsl = 15;
      if (oc0 >= 0 && ovis0 != row) {
        float io2 = iou_f32(ob0, tbi, ati);
        double cur = ((-(double)io2) - u_i0) - ov0;   // exact reference f64 op order
        u64 mk = map_cost(cur);
        bhi = (u32)(mk >> 32); blo = (u32)mk; bcol = oc0; bsl = 6;
      }
      if (oc1 >= 0 && ovis1 != row) {
        float io2 = iou_f32(ob1, tbi, ati);
        double cur = ((-(double)io2) - u_i0) - ov1;
        u64 mk = map_cost(cur);
        u32 hi = (u32)(mk >> 32), lo = (u32)mk;
        bool t = (hi < bhi) || (hi == bhi && ((lo < blo) || (lo == blo && oc1 < bcol)));
        if (t) { bhi = hi; blo = lo; bcol = oc1; bsl = 7; }
      }
      // ---- hi-word DPP min; lo/col tie-break on rare uniform branches ----
      u32 khi = bhi;
      DPPMINH(0x111); DPPMINH(0x112); DPPMINH(0x114); DPPMINH(0x118);
      DPPMINH(0x142); DPPMINH(0x143);
      u32 rhi = (u32)__builtin_amdgcn_readlane((int)khi, 63);
      u64 wm = __ballot(bhi == rhi);
      int L; u32 rlo; int rcol;
      if (__popcll(wm) == 1) {
        L = (int)__ffsll((long long)wm) - 1;
        L = __builtin_amdgcn_readfirstlane(L);
        rlo = (u32)__builtin_amdgcn_readlane((int)blo, L);
        rcol = __builtin_amdgcn_readlane(bcol, L);
      } else {
        u32 klo2 = (bhi == rhi) ? blo : 0xFFFFFFFFu;
        DPPMINL(0x111); DPPMINL(0x112); DPPMINL(0x114); DPPMINL(0x118);
        DPPMINL(0x142); DPPMINL(0x143);
        rlo = (u32)__builtin_amdgcn_readlane((int)klo2, 63);
        bool eq2 = (bhi == rhi) && (blo == rlo);
        u64 wm2 = __ballot(eq2);
        if (__popcll(wm2) == 1) {
          L = (int)__ffsll((long long)wm2) - 1;
          L = __builtin_amdgcn_readfirstlane(L);
          rcol = __builtin_amdgcn_readlane(bcol, L);
        } else {
          int cc = eq2 ? bcol : 0x7fffffff;
          DPPMINC(0x111); DPPMINC(0x112); DPPMINC(0x114); DPPMINC(0x118);
          DPPMINC(0x142); DPPMINC(0x143);
          rcol = __builtin_amdgcn_readlane(cc, 63);
          L = (int)__ffsll((long long)__ballot(eq2 && bcol == rcol)) - 1;
          L = __builtin_amdgcn_readfirstlane(L);
        }
      }

      // ---- head cost (fresh best; v==0 exact) ----
      float hio = __uint_as_float((u32)(head_key >> 32));
      int hcol = (int)(0xFFFFFFFFu - (u32)head_key);
      double curh = (-(double)hio) - u_i0;          // == ((-io)-u)-0.0 bitwise
      u64 mhc = map_cost(curh);
      u32 hhi = (u32)(mhc >> 32), hlo = (u32)mhc;
      bool head_wins = (hhi < rhi) || (hhi == rhi && ((hlo < rlo) || (hlo == rlo && hcol < rcol)));
      const double delta = unmap_cost(head_wins ? mhc : (((u64)rhi << 32) | (u64)rlo));

      // ---- updates: u[p[used]] += delta ; v[used] -= delta (pre-append set) ----
      if (f_a) u_a += delta;
      if (f_b) u_b += delta;
      u_i0 += delta;
      if (oc0 >= 0 && ovis0 == row) ov0 -= delta;
      if (oc1 >= 0 && ovis1 == row) ov1 -= delta;

      if (head_wins) {
        const int jc = hcol;
        if (lane == 0) s_pairs[row - 1] = jc;
        if (row == NROWS) break;
        // winner box: i0's head entry (read ptr BEFORE walks advance it)
        int iw = i0 - 1;
        int pw = __builtin_amdgcn_readlane((iw >> 6) ? p1 : p0, iw & 63);
        float4 hbox;
        if (pw < TOP8) hbox = s_t8b[iw * TOP8 + pw];    // uniform addr -> LDS broadcast
        else hbox = pbox[jc];                           // fallback-headed winner (rare)
        // ---- advance heads whose col == jc (old mask + explicit jc test) ----
        u32 jw = (u32)jc;
        bool adv0 = h0 && ((0xFFFFFFFFu - (u32)h0) == jw);
        if (adv0) {
          int p = p0; u64 k;
          for (;;) {
            ++p;
            k = (p < TOP8) ? s_t8[lane * TOP8 + p] : 0;
            if (!k) break;
            u32 c = 0xFFFFFFFFu - (u32)k;
            if (c != jw && !((s_mask[c >> 5] >> (c & 31u)) & 1u)) break;
          }
          h0 = k; p0 = p;
        }
        bool adv1 = h1 && ((0xFFFFFFFFu - (u32)h1) == jw);
        if (adv1) {
          int p = p1; u64 k;
          for (;;) {
            ++p;
            k = (p < TOP8) ? s_t8[(lane + 64) * TOP8 + p] : 0;
            if (!k) break;
            u32 c = 0xFFFFFFFFu - (u32)k;
            if (c != jw && !((s_mask[c >> 5] >> (c & 31u)) & 1u)) break;
          }
          h1 = k; p1 = p;
        }
        // ---- rare fallback: a row exhausted its top8 -> full-pool scan ----
        u64 fb0 = __ballot(adv0 && h0 == 0);
        u64 fb1 = __ballot(adv1 && h1 == 0);
        while (fb0 | fb1) {
          bool s1 = (fb0 == 0);
          u64 mcur = s1 ? fb1 : fb0;
          int L2 = (int)__ffsll((long long)mcur) - 1;
          L2 = __builtin_amdgcn_readfirstlane(L2);
          int rw = L2 + (s1 ? 64 : 0);
          const u64* kp2 = ckey + (size_t)rw * CAND;
          u64 lmax = 0;
#pragma unroll
          for (int s2 = 0; s2 < NSLOT; ++s2) {
            u64 kf = kp2[(s2 << 6) + lane];
            if (kf) {
              u32 c = 0xFFFFFFFFu - (u32)kf;
              if (c == jw || ((s_mask[c >> 5] >> (c & 31u)) & 1u)) kf = 0;
              if (kf > lmax) lmax = kf;
            }
          }
          u32 mhi = (u32)(lmax >> 32), mlo = (u32)lmax;
          DPPMAX(0x111); DPPMAX(0x112); DPPMAX(0x114); DPPMAX(0x118);
          DPPMAX(0x142); DPPMAX(0x143);
          u32 g2hi = (u32)__builtin_amdgcn_readlane((int)mhi, 63);
          u32 g2lo = (u32)__builtin_amdgcn_readlane((int)mlo, 63);
          u64 g = ((u64)g2hi << 32) | (u64)g2lo;
          if (lane == L2) { if (s1) { h1 = g; p1 = TOP8; } else { h0 = g; p0 = TOP8; } }
          if (s1) fb1 &= fb1 - 1; else fb0 &= fb0 - 1;
        }
        // ---- record ownership (after walks; same-wave DS FIFO orders later reads) ----
        if (lane == 0) atomicOr(&s_mask[jw >> 5], 1u << (jw & 31u));
        // ---- insert owned slot ----
        {
          int nl = nown & 63, nh = nown >> 6;
          if (lane == nl) {
            if (nh == 0) { oc0 = jc; orow0 = row; ovis0 = 0; ov0 = 0.0; ob0 = hbox; }
            else         { oc1 = jc; orow1 = row; ovis1 = 0; ov1 = 0.0; ob1 = hbox; }
          }
          ++nown;
        }
        ++row; i0 = row; u_i0 = 0.0;
        f_a = (lane == ((row - 1) & 63)) && (((row - 1) >> 6) == 0);
        f_b = (lane == ((row - 1) & 63)) && (((row - 1) >> 6) == 1);
      } else {
        // ---- chain to owner row: registers + readlanes only ----
        int s_w = __builtin_amdgcn_readlane(bsl, L);
        int o = __builtin_amdgcn_readlane((s_w == 6) ? orow0 : orow1, L);
        o = __builtin_amdgcn_readfirstlane(o);
        if (lane == L) { if (s_w == 6) ovis0 = row; else ovis1 = row; }
        int ol = (o - 1) & 63, oh = (o - 1) >> 6;
        if (lane == ol) { if (oh == 0) f_a = 1; else f_b = 1; }
        double uo = oh ? u_b : u_a;
        int uhi2 = __builtin_amdgcn_readlane(__double2hiint(uo), ol);
        int ulo2 = __builtin_amdgcn_readlane(__double2loint(uo), ol);
        u_i0 = __hiloint2double(uhi2, ulo2);
        i0 = o;
      }
    }
  }
  __syncthreads();

  // ---- fused loss phase (all 256 threads) ----
  float reg = 0.0f, cls = 0.0f; int acc = 0;
  if (tid < NROWS) {
    int pred = s_pairs[tid];
    float4 pb = pbox[pred];
    float4 tb = tboxg[tid];
    float d0 = pb.x - tb.x, d1 = pb.y - tb.y, d2 = pb.z - tb.z, d3 = pb.w - tb.w;
    float a0 = fabsf(d0), a1 = fabsf(d1), a2 = fabsf(d2), a3 = fabsf(d3);
    float s = 0.0f;
    s += (a0 < 1.0f) ? 0.5f * d0 * d0 : a0 - 0.5f;
    s += (a1 < 1.0f) ? 0.5f * d1 * d1 : a1 - 0.5f;
    s += (a2 < 1.0f) ? 0.5f * d2 * d2 : a2 - 0.5f;
    s += (a3 < 1.0f) ? 0.5f * d3 * d3 : a3 - 0.5f;
    reg = s * 0.25f;

    const float* lg = confs + (long long)pred * C;
    float mx = lg[0]; int am = 0;
    for (int k = 1; k < C; ++k) { float x = lg[k]; if (x > mx) { mx = x; am = k; } }
    double se = 0.0;
    for (int k = 0; k < C; ++k) se += exp((double)(lg[k] - mx));
    int lab = tlab[tid];
    double logp = (double)(lg[lab] - mx) - log(se);
    cls = (float)(-logp);
    acc = (am == lab) ? 1 : 0;
  }
  s_reg[tid] = reg; s_cls[tid] = cls; s_acc[tid] = acc;
  __syncthreads();
  for (int s2 = 128; s2 > 0; s2 >>= 1) {
    if (tid < s2) {
      s_reg[tid] += s_reg[tid + s2];
      s_cls[tid] += s_cls[tid + s2];
      s_acc[tid] += s_acc[tid + s2];
    }
    __syncthreads();
  }
  if (tid == 0) {
    out[0] = s_reg[0] + s_cls[0];
    out[1] = (float)s_acc[0];
  }
}

extern "C" void kernel_launch(void* const* d_in, const int* in_sizes, int n_in,
                              void* d_out, int out_size, void* d_ws, size_t ws_size,
                              hipStream_t stream) {
  const float4* pbox  = (const float4*)d_in[0];
  const float*  confs = (const float*)d_in[1];
  const float4* tbox  = (const float4*)d_in[2];
  const int*    tlab  = (const int*)d_in[3];

  int N = in_sizes[0] / 4;          // 100000 predictions (columns)
  int C = in_sizes[1] / N;          // 81 classes
  int NROWS = in_sizes[2] / 4;      // 128 targets (rows), <=128 supported
  int M = N;

  char* w = (char*)d_ws;
  auto alloc = [&](size_t sz) { char* r = w; w += (sz + 255) & ~(size_t)255; return r; };
  u64*    ckey  = (u64*)   alloc((size_t)NROWS * CAND * sizeof(u64));
  u64*    top8g = (u64*)   alloc((size_t)NROWS * TOP8 * sizeof(u64));
  float4* top8b = (float4*)alloc((size_t)NROWS * TOP8 * sizeof(float4));

  select_kernel<<<dim3(SLICES, NROWS), SEL_THR, 0, stream>>>(pbox, tbox, ckey, M, NROWS);
  top8_kernel<<<NROWS, 64, 0, stream>>>(pbox, ckey, top8g, top8b, NROWS);
  match_kernel<<<1, 256, 0, stream>>>(pbox, tbox, ckey, top8g, top8b,
                                      confs, tlab, (float*)d_out, M, NROWS, C);
}